// Round 6
// baseline (864.464 us; speedup 1.0000x reference)
//
#include <hip/hip_runtime.h>

// FlowExp: v = flow/2^8; repeat 8x: v <- trilinear_pull(v, identity + v)
// Invariant: ||v||inf <= max|flow|/256 ~ 0.023 < 1 for all steps (each step is
// a convex combination of previous values, zero-masked outside). Hence
// floor(x+vx) is x-1 (vx<0) or x (vx>=0): no clamps, just a sign test, and a
// halo of 1 in LDS always covers both corners. Out-of-bounds samples handled
// by folding the inb mask into the z-weights.
//
// R6 structure: (A) own-voxel displacements loaded from GLOBAL up front
// (coalesced; same cache lines staging reads -> ~no extra HBM) so the gather
// has no own-read LDS dependency; (B) per-float coalesced staging (R4-proven
// FETCH); (C) sync; (D) gather: corner addresses from registers, 24 b32 LDS
// reads + 24 FMA per output, unroll 2 for MLP.

#define BB 2
#define DD 160
#define HH 192
#define WW 160

constexpr int HW    = HH * WW;          // 30720
constexpr int PLANE = DD * HW;          // 4,915,200
constexpr int TX = 32, TY = 8, TZ = 8;
constexpr int SX = TX + 2, SY = TY + 2, SZ = TZ + 2;   // 34 x 10 x 10
constexpr int SYX = SY * SX;            // 340
constexpr int NW  = SZ * SYX;           // 3400
constexpr int NF  = 3 * NW;             // 10200
constexpr int NITERF = (NF + 255) / 256;   // 40

// IN_FMT : 0 = planar (B,3,D,H,W) scaled by `scale` (step 1 reads flow)
//          1 = packed interleaved (B,D,H,W,3)
// OUT_FMT: 0 = planar (final step), 1 = packed
template<int IN_FMT, int OUT_FMT>
__global__ __launch_bounds__(256, 3) void flow_step(const float* __restrict__ vin,
                                                    float* __restrict__ vout,
                                                    float scale) {
    __shared__ float lds[NF];
    const int tid = threadIdx.x;
    const int x0 = blockIdx.x * TX;
    const int y0 = blockIdx.y * TY;
    const int b  = blockIdx.z / (DD / TZ);
    const int z0 = (blockIdx.z % (DD / TZ)) * TZ;
    const int tx = tid & (TX - 1);
    const int ty = tid >> 5;
    const int x = x0 + tx, y = y0 + ty;

    // ---- A: own-voxel displacements from global, all TZ up front ----
    float own[TZ][3];
    #pragma unroll
    for (int zz = 0; zz < TZ; ++zz) {
        const int z = z0 + zz;
        if (IN_FMT == 0) {
            const float* bp = vin + (size_t)b * 3 * PLANE + (z * HH + y) * WW + x;
            own[zz][0] = bp[0] * scale;
            own[zz][1] = bp[PLANE] * scale;
            own[zz][2] = bp[2 * PLANE] * scale;
        } else {
            const float* bp = vin + ((size_t)((b * DD + z) * HH + y) * WW + x) * 3;
            own[zz][0] = bp[0]; own[zz][1] = bp[1]; own[zz][2] = bp[2];
        }
    }

    // ---- B: stage tile+halo, one float per lane per iter (coalesced) ----
    const bool border = (x0 == 0) | (x0 + TX >= WW) |
                        (y0 == 0) | (y0 + TY >= HH) |
                        (z0 == 0) | (z0 + TZ >= DD);
    const int gb0 = ((z0 - 1) * HH + (y0 - 1)) * WW + (x0 - 1);  // interior tile origin
    #pragma unroll 8
    for (int k = 0; k < NITERF; ++k) {
        int i = tid + k * 256;
        i = min(i, NF - 1);                 // tail: duplicate write, same value
        int ch, vox;
        if (IN_FMT == 0) { ch = i / NW; vox = i - ch * NW; }
        else             { vox = i / 3; ch = i - vox * 3; }
        const int szi = vox / SYX;
        const int r   = vox - szi * SYX;
        const int syi = r / SX;
        const int sxi = r - syi * SX;
        int pa;                              // voxel offset within batch b
        if (!border) {
            pa = gb0 + szi * HW + syi * WW + sxi;
        } else {
            const int gz = min(max(z0 - 1 + szi, 0), DD - 1);
            const int gy = min(max(y0 - 1 + syi, 0), HH - 1);
            const int gx = min(max(x0 - 1 + sxi, 0), WW - 1);
            pa = (gz * HH + gy) * WW + gx;
        }
        float val;
        if (IN_FMT == 0) val = vin[(size_t)(b * 3 + ch) * PLANE + pa] * scale;
        else             val = vin[((size_t)b * PLANE + pa) * 3 + ch];
        lds[ch * NW + vox] = val;            // stride-1 across lanes: conflict-free
    }
    __syncthreads();

    // ---- D: gather, all addressing from registers ----
    #pragma unroll 2
    for (int zz = 0; zz < TZ; ++zz) {
        const int z = z0 + zz;
        const float vz = own[zz][0], vy = own[zz][1], vx = own[zz][2];
        const float cz = (float)z + vz, cy = (float)y + vy, cx = (float)x + vx;

        const bool jz = vz < 0.f, jy = vy < 0.f, jx = vx < 0.f;
        const float gzf = jz ? vz + 1.f : vz;    // == frac(z+vz) (|v|<1)
        const float gyf = jy ? vy + 1.f : vy;
        const float gxf = jx ? vx + 1.f : vx;

        const bool inb = (cz >= 0.f) & (cz <= (float)(DD - 1)) &
                         (cy >= 0.f) & (cy <= (float)(HH - 1)) &
                         (cx >= 0.f) & (cx <= (float)(WW - 1));
        const float m = inb ? 1.f : 0.f;
        const float wz1 = gzf * m, wz0 = m - wz1;
        const float wy1 = gyf,     wy0 = 1.f - gyf;
        const float wx1 = gxf,     wx0 = 1.f - gxf;

        const int so = ((zz + 1) * SY + (ty + 1)) * SX + (tx + 1);
        const int sb = ((so - (jx ? 1 : 0)) - (jy ? SX : 0)) - (jz ? SYX : 0);

        float oz = 0.f, oy = 0.f, ox = 0.f;
        #pragma unroll
        for (int dz = 0; dz < 2; ++dz) {
            const float wzv = dz ? wz1 : wz0;
            #pragma unroll
            for (int dy = 0; dy < 2; ++dy) {
                const float wzy = wzv * (dy ? wy1 : wy0);
                const float w0 = wzy * wx0, w1 = wzy * wx1;
                const int o = sb + dz * SYX + dy * SX;   // imm offsets vs sb
                oz += lds[o] * w0;              oy += lds[NW + o] * w0;
                ox += lds[2 * NW + o] * w0;
                oz += lds[o + 1] * w1;          oy += lds[NW + o + 1] * w1;
                ox += lds[2 * NW + o + 1] * w1;
            }
        }

        if (OUT_FMT == 0) {
            float* bp = vout + (size_t)b * 3 * PLANE + (z * HH + y) * WW + x;
            bp[0] = oz; bp[PLANE] = oy; bp[2 * PLANE] = ox;
        } else {
            float t[3] = { oz, oy, ox };
            __builtin_memcpy(vout + ((size_t)((b * DD + z) * HH + y) * WW + x) * 3, t, 12);
        }
    }
}

extern "C" void kernel_launch(void* const* d_in, const int* in_sizes, int n_in,
                              void* d_out, int out_size, void* d_ws, size_t ws_size,
                              hipStream_t stream) {
    const float* flow = (const float*)d_in[0];
    float* out = (float*)d_out;   // doubles as packed scratch for even steps
    float* wsA = (float*)d_ws;    // packed scratch (118 MB)

    dim3 blk(256);
    dim3 grd(WW / TX, HH / TY, (DD / TZ) * BB);   // 5 x 24 x 40
    const float s = 1.f / 256.f;                  // 1 / 2^NSTEPS

    flow_step<0, 1><<<grd, blk, 0, stream>>>(flow, wsA, s);
    flow_step<1, 1><<<grd, blk, 0, stream>>>(wsA, out, 1.f);
    flow_step<1, 1><<<grd, blk, 0, stream>>>(out, wsA, 1.f);
    flow_step<1, 1><<<grd, blk, 0, stream>>>(wsA, out, 1.f);
    flow_step<1, 1><<<grd, blk, 0, stream>>>(out, wsA, 1.f);
    flow_step<1, 1><<<grd, blk, 0, stream>>>(wsA, out, 1.f);
    flow_step<1, 1><<<grd, blk, 0, stream>>>(out, wsA, 1.f);
    flow_step<1, 0><<<grd, blk, 0, stream>>>(wsA, out, 1.f);
}

// Round 7
// 767.550 us; speedup vs baseline: 1.1263x; 1.1263x over previous
//
#include <hip/hip_runtime.h>

// FlowExp: v = flow/2^8; repeat 8x: v <- trilinear_pull(v, identity + v)
// Invariant: ||v||inf <= max|flow|/256 ~ 0.023 < 1 for all steps (each step is
// a convex combination of previous values, zero-masked outside). Hence
// floor(x+vx) is x-1 (vx<0) or x (vx>=0): no clamps, just sign tests, and a
// halo of 1 in LDS always covers both corners. Out-of-bounds samples handled
// by folding the inb mask into the z-weights (all 8 weights become 0).
//
// R7: LDS-issue-bound -> cut LDS ops/voxel ~2x.
//  * channels (0,1) packed as aligned float2 plane + separate ch2 plane:
//    corner = 1 ds_read_b64 + 1 b32 (was 3 b32); x-pair reads mergeable.
//  * ALL intermediates planar (B,3,D,H,W): staging = 3 coalesced dword
//    streams (R4-proven FETCH), per-voxel loop (14 iters), single template.
//  * own-voxel from LDS (R6's global-own failed), sign-test addressing.

#define BB 2
#define DD 160
#define HH 192
#define WW 160

constexpr int HW    = HH * WW;          // 30720
constexpr int PLANE = DD * HW;          // 4,915,200
constexpr int TX = 32, TY = 8, TZ = 8;
constexpr int SX = TX + 2, SY = TY + 2, SZ = TZ + 2;   // 34 x 10 x 10
constexpr int SYX = SY * SX;            // 340
constexpr int NW  = SZ * SYX;           // 3400
constexpr int NITER = (NW + 255) / 256; // 14

__global__ __launch_bounds__(256, 3) void flow_step(const float* __restrict__ vin,
                                                    float* __restrict__ vout,
                                                    float scale) {
    __shared__ float2 lds01[NW];   // channels z,y packed (8B aligned)
    __shared__ float  lds2[NW];    // channel x
    const int tid = threadIdx.x;
    const int x0 = blockIdx.x * TX;
    const int y0 = blockIdx.y * TY;
    const int b  = blockIdx.z / (DD / TZ);
    const int z0 = (blockIdx.z % (DD / TZ)) * TZ;
    const size_t bofs = (size_t)b * 3 * PLANE;

    // ---- stage tile+halo: per-voxel, 3 coalesced dword streams ----
    const bool border = (x0 == 0) | (x0 + TX >= WW) |
                        (y0 == 0) | (y0 + TY >= HH) |
                        (z0 == 0) | (z0 + TZ >= DD);
    const int gb0 = ((z0 - 1) * HH + (y0 - 1)) * WW + (x0 - 1);  // interior origin
    #pragma unroll
    for (int k = 0; k < NITER; ++k) {
        int vox = tid + k * 256;
        vox = min(vox, NW - 1);              // tail: duplicate write, same value
        const int szi = vox / SYX;
        const int r   = vox - szi * SYX;
        const int syi = r / SX;
        const int sxi = r - syi * SX;
        int pa;                              // voxel offset within batch b
        if (!border) {
            pa = gb0 + szi * HW + syi * WW + sxi;
        } else {
            const int gz = min(max(z0 - 1 + szi, 0), DD - 1);
            const int gy = min(max(y0 - 1 + syi, 0), HH - 1);
            const int gx = min(max(x0 - 1 + sxi, 0), WW - 1);
            pa = (gz * HH + gy) * WW + gx;
        }
        const float* bp = vin + bofs + pa;
        const float c0 = bp[0] * scale;
        const float c1 = bp[PLANE] * scale;
        const float c2 = bp[2 * PLANE] * scale;
        lds01[vox] = make_float2(c0, c1);    // one ds_write_b64, stride-2-dword lanes
        lds2[vox]  = c2;                     // stride-1: conflict-free
    }
    __syncthreads();

    // ---- gather: 8 output voxels per thread ----
    const int tx = tid & (TX - 1);
    const int ty = tid >> 5;
    const int x = x0 + tx, y = y0 + ty;

    #pragma unroll 2
    for (int zz = 0; zz < TZ; ++zz) {
        const int z = z0 + zz;
        const int so = ((zz + 1) * SY + (ty + 1)) * SX + (tx + 1);
        const float2 o01 = lds01[so];
        const float vz = o01.x, vy = o01.y, vx = lds2[so];
        const float cz = (float)z + vz, cy = (float)y + vy, cx = (float)x + vx;

        const bool jz = vz < 0.f, jy = vy < 0.f, jx = vx < 0.f;
        const float gzf = jz ? vz + 1.f : vz;    // == frac(z+vz) up to ulp
        const float gyf = jy ? vy + 1.f : vy;
        const float gxf = jx ? vx + 1.f : vx;

        const bool inb = (cz >= 0.f) & (cz <= (float)(DD - 1)) &
                         (cy >= 0.f) & (cy <= (float)(HH - 1)) &
                         (cx >= 0.f) & (cx <= (float)(WW - 1));
        const float m = inb ? 1.f : 0.f;
        const float wz1 = gzf * m, wz0 = m - wz1;
        const float wy1 = gyf,     wy0 = 1.f - gyf;
        const float wx1 = gxf,     wx0 = 1.f - gxf;

        const int sb = ((so - (jx ? 1 : 0)) - (jy ? SX : 0)) - (jz ? SYX : 0);

        float oz = 0.f, oy = 0.f, ox = 0.f;
        #pragma unroll
        for (int dz = 0; dz < 2; ++dz) {
            const float wzv = dz ? wz1 : wz0;
            #pragma unroll
            for (int dy = 0; dy < 2; ++dy) {
                const float wzy = wzv * (dy ? wy1 : wy0);
                const float w0 = wzy * wx0, w1 = wzy * wx1;
                const int o = sb + dz * SYX + dy * SX;
                const float2 pa = lds01[o];        // ds_read_b64 (aligned)
                const float2 pb = lds01[o + 1];    // ds_read_b64 (aligned)
                const float  qa = lds2[o];         // mergeable ds_read2_b32
                const float  qb = lds2[o + 1];
                // reference corner order: dx=0 then dx=1, same weight all ch
                oz += pa.x * w0; oy += pa.y * w0; ox += qa * w0;
                oz += pb.x * w1; oy += pb.y * w1; ox += qb * w1;
            }
        }

        float* op = vout + bofs + (z * HH + y) * WW + x;
        op[0] = oz; op[PLANE] = oy; op[2 * PLANE] = ox;
    }
}

extern "C" void kernel_launch(void* const* d_in, const int* in_sizes, int n_in,
                              void* d_out, int out_size, void* d_ws, size_t ws_size,
                              hipStream_t stream) {
    const float* flow = (const float*)d_in[0];
    float* out = (float*)d_out;   // planar scratch for even steps + final output
    float* wsA = (float*)d_ws;    // planar scratch (118 MB)

    dim3 blk(256);
    dim3 grd(WW / TX, HH / TY, (DD / TZ) * BB);   // 5 x 24 x 40
    const float s = 1.f / 256.f;                  // 1 / 2^NSTEPS

    flow_step<<<grd, blk, 0, stream>>>(flow, wsA, s);
    flow_step<<<grd, blk, 0, stream>>>(wsA, out, 1.f);
    flow_step<<<grd, blk, 0, stream>>>(out, wsA, 1.f);
    flow_step<<<grd, blk, 0, stream>>>(wsA, out, 1.f);
    flow_step<<<grd, blk, 0, stream>>>(out, wsA, 1.f);
    flow_step<<<grd, blk, 0, stream>>>(wsA, out, 1.f);
    flow_step<<<grd, blk, 0, stream>>>(out, wsA, 1.f);
    flow_step<<<grd, blk, 0, stream>>>(wsA, out, 1.f);
}

// Round 8
// 549.218 us; speedup vs baseline: 1.5740x; 1.3975x over previous
//
#include <hip/hip_runtime.h>

// FlowExp: v = flow/2^8; repeat 8x: v <- trilinear_pull(v, identity + v)
// Invariant: ||v||inf <= max|flow|/256 ~ 0.023 < 1 for all steps, so
// floor(x+vx) in {x-1, x}: sign tests instead of floor/mod/clamp, halo 1
// always covers the corners, out-of-bounds folded into z-weights (m=0).
//
// R8: latency-bound diagnosis -> (a) staging via global_load_lds async DMA
// (no VGPR round-trip, deep vmcnt queue), which forces LDS layout == global
// order -> interleaved (B,D,H,W,3) buffers for steps 2..8 (also the proven
// 189MB-FETCH layout); (b) LDS = 40960B exactly -> 4 blocks/CU, declare it.

#define BB 2
#define DD 160
#define HH 192
#define WW 160

constexpr int HW    = HH * WW;          // 30720
constexpr int PLANE = DD * HW;          // 4,915,200
constexpr int TX = 32, TY = 8, TZ = 8;
constexpr int SX = TX + 2, SY = TY + 2, SZ = TZ + 2;   // 34 x 10 x 10
constexpr int SYX = SY * SX;            // 340
constexpr int NW  = SZ * SYX;           // 3400 voxels per tile
constexpr int NF  = 3 * NW;             // 10200 floats per tile
constexpr int NFULL = NF / 256;         // 39 full 256-float DMA iterations
constexpr int NREM  = NF - NFULL * 256; // 216 remainder floats

__device__ __forceinline__ void gld_lds4(const float* g, float* l) {
    __builtin_amdgcn_global_load_lds(
        (const __attribute__((address_space(1))) void*)g,
        (__attribute__((address_space(3))) void*)l, 4, 0, 0);
}

// in-batch voxel offset for staging element `vox` of the tile (+border clamp)
__device__ __forceinline__ int stage_pa(int vox, int x0, int y0, int z0,
                                        int gb0, bool border) {
    const int szi = vox / SYX;
    const int r   = vox - szi * SYX;
    const int syi = r / SX;
    const int sxi = r - syi * SX;
    if (!border) return gb0 + szi * HW + syi * WW + sxi;
    const int gz = min(max(z0 - 1 + szi, 0), DD - 1);
    const int gy = min(max(y0 - 1 + syi, 0), HH - 1);
    const int gx = min(max(x0 - 1 + sxi, 0), WW - 1);
    return (gz * HH + gy) * WW + gx;
}

// ---------------- step 1: planar flow (x scale) -> packed interleaved ------
__global__ __launch_bounds__(256, 4) void flow_first(const float* __restrict__ vin,
                                                     float* __restrict__ vout,
                                                     float scale) {
    __shared__ float lds[NF];   // SoA: 3 planes of NW
    const int tid = threadIdx.x;
    const int x0 = blockIdx.x * TX;
    const int y0 = blockIdx.y * TY;
    const int b  = blockIdx.z / (DD / TZ);
    const int z0 = (blockIdx.z % (DD / TZ)) * TZ;
    const bool border = (x0 == 0) | (x0 + TX >= WW) |
                        (y0 == 0) | (y0 + TY >= HH) |
                        (z0 == 0) | (z0 + TZ >= DD);
    const int gb0 = ((z0 - 1) * HH + (y0 - 1)) * WW + (x0 - 1);

    #pragma unroll 8
    for (int k = 0; k < (NF + 255) / 256; ++k) {
        int i = min(tid + k * 256, NF - 1);     // tail: dup write, same value
        const int ch  = i / NW;
        const int vox = i - ch * NW;
        const int pa  = stage_pa(vox, x0, y0, z0, gb0, border);
        lds[i] = vin[(size_t)(b * 3 + ch) * PLANE + pa] * scale;
    }
    __syncthreads();

    const int tx = tid & (TX - 1), ty = tid >> 5;
    const int x = x0 + tx, y = y0 + ty;
    #pragma unroll 2
    for (int zz = 0; zz < TZ; ++zz) {
        const int z = z0 + zz;
        const int so = ((zz + 1) * SY + (ty + 1)) * SX + (tx + 1);
        const float vz = lds[so], vy = lds[NW + so], vx = lds[2 * NW + so];
        const float cz = (float)z + vz, cy = (float)y + vy, cx = (float)x + vx;
        const bool jz = vz < 0.f, jy = vy < 0.f, jx = vx < 0.f;
        const float gzf = jz ? vz + 1.f : vz;
        const float gyf = jy ? vy + 1.f : vy;
        const float gxf = jx ? vx + 1.f : vx;
        const bool inb = (cz >= 0.f) & (cz <= (float)(DD - 1)) &
                         (cy >= 0.f) & (cy <= (float)(HH - 1)) &
                         (cx >= 0.f) & (cx <= (float)(WW - 1));
        const float m = inb ? 1.f : 0.f;
        const float wz1 = gzf * m, wz0 = m - wz1;
        const float wy1 = gyf, wy0 = 1.f - gyf;
        const float wx1 = gxf, wx0 = 1.f - gxf;
        const int sb = ((so - (jx ? 1 : 0)) - (jy ? SX : 0)) - (jz ? SYX : 0);
        float oz = 0.f, oy = 0.f, ox = 0.f;
        #pragma unroll
        for (int dz = 0; dz < 2; ++dz) {
            const float wzv = dz ? wz1 : wz0;
            #pragma unroll
            for (int dy = 0; dy < 2; ++dy) {
                const float wzy = wzv * (dy ? wy1 : wy0);
                const float w0 = wzy * wx0, w1 = wzy * wx1;
                const int o = sb + dz * SYX + dy * SX;
                oz += lds[o] * w0;     oy += lds[NW + o] * w0;     ox += lds[2 * NW + o] * w0;
                oz += lds[o + 1] * w1; oy += lds[NW + o + 1] * w1; ox += lds[2 * NW + o + 1] * w1;
            }
        }
        float t[3] = { oz, oy, ox };
        __builtin_memcpy(vout + ((size_t)((b * DD + z) * HH + y) * WW + x) * 3, t, 12);
    }
}

// ------------- steps 2..8: packed interleaved in, DMA staging --------------
// OUT_PLANAR: final step writes (B,3,D,H,W)
template<int OUT_PLANAR>
__global__ __launch_bounds__(256, 4) void flow_mid(const float* __restrict__ vin,
                                                   float* __restrict__ vout) {
    __shared__ float lds[NF];   // interleaved: voxel v -> floats 3v..3v+2
    const int tid = threadIdx.x;
    const int x0 = blockIdx.x * TX;
    const int y0 = blockIdx.y * TY;
    const int b  = blockIdx.z / (DD / TZ);
    const int z0 = (blockIdx.z % (DD / TZ)) * TZ;
    const bool border = (x0 == 0) | (x0 + TX >= WW) |
                        (y0 == 0) | (y0 + TY >= HH) |
                        (z0 == 0) | (z0 + TZ >= DD);
    const int gb0 = ((z0 - 1) * HH + (y0 - 1)) * WW + (x0 - 1);
    const float* vb = vin + (size_t)b * PLANE * 3;

    // async DMA staging: LDS linear == global interleaved order
    #pragma unroll 8
    for (int k = 0; k < NFULL; ++k) {
        const int i = tid + k * 256;
        const int vox = i / 3;
        const int ch  = i - vox * 3;
        const int pa  = stage_pa(vox, x0, y0, z0, gb0, border);
        gld_lds4(vb + (size_t)pa * 3 + ch, &lds[i]);
    }
    if (tid < NREM) {   // tail via plain write (DMA dest is HW-linear)
        const int i = tid + NFULL * 256;
        const int vox = i / 3;
        const int ch  = i - vox * 3;
        const int pa  = stage_pa(vox, x0, y0, z0, gb0, border);
        lds[i] = vb[(size_t)pa * 3 + ch];
    }
    __syncthreads();

    const int tx = tid & (TX - 1), ty = tid >> 5;
    const int x = x0 + tx, y = y0 + ty;
    #pragma unroll 2
    for (int zz = 0; zz < TZ; ++zz) {
        const int z = z0 + zz;
        const int so = ((zz + 1) * SY + (ty + 1)) * SX + (tx + 1);
        const float vz = lds[3 * so], vy = lds[3 * so + 1], vx = lds[3 * so + 2];
        const float cz = (float)z + vz, cy = (float)y + vy, cx = (float)x + vx;
        const bool jz = vz < 0.f, jy = vy < 0.f, jx = vx < 0.f;
        const float gzf = jz ? vz + 1.f : vz;
        const float gyf = jy ? vy + 1.f : vy;
        const float gxf = jx ? vx + 1.f : vx;
        const bool inb = (cz >= 0.f) & (cz <= (float)(DD - 1)) &
                         (cy >= 0.f) & (cy <= (float)(HH - 1)) &
                         (cx >= 0.f) & (cx <= (float)(WW - 1));
        const float m = inb ? 1.f : 0.f;
        const float wz1 = gzf * m, wz0 = m - wz1;
        const float wy1 = gyf, wy0 = 1.f - gyf;
        const float wx1 = gxf, wx0 = 1.f - gxf;
        const int sb = ((so - (jx ? 1 : 0)) - (jy ? SX : 0)) - (jz ? SYX : 0);
        float oz = 0.f, oy = 0.f, ox = 0.f;
        #pragma unroll
        for (int dz = 0; dz < 2; ++dz) {
            const float wzv = dz ? wz1 : wz0;
            #pragma unroll
            for (int dy = 0; dy < 2; ++dy) {
                const float wzy = wzv * (dy ? wy1 : wy0);
                const float w0 = wzy * wx0, w1 = wzy * wx1;
                const int ob = 3 * (sb + dz * SYX + dy * SX);
                oz += lds[ob]     * w0; oy += lds[ob + 1] * w0; ox += lds[ob + 2] * w0;
                oz += lds[ob + 3] * w1; oy += lds[ob + 4] * w1; ox += lds[ob + 5] * w1;
            }
        }
        if (OUT_PLANAR) {
            float* op = vout + (size_t)b * 3 * PLANE + (z * HH + y) * WW + x;
            op[0] = oz; op[PLANE] = oy; op[2 * PLANE] = ox;
        } else {
            float t[3] = { oz, oy, ox };
            __builtin_memcpy(vout + ((size_t)((b * DD + z) * HH + y) * WW + x) * 3, t, 12);
        }
    }
}

extern "C" void kernel_launch(void* const* d_in, const int* in_sizes, int n_in,
                              void* d_out, int out_size, void* d_ws, size_t ws_size,
                              hipStream_t stream) {
    const float* flow = (const float*)d_in[0];
    float* out = (float*)d_out;   // packed scratch for even steps + final planar
    float* wsA = (float*)d_ws;    // packed scratch (118 MB)

    dim3 blk(256);
    dim3 grd(WW / TX, HH / TY, (DD / TZ) * BB);   // 5 x 24 x 40
    const float s = 1.f / 256.f;                  // 1 / 2^NSTEPS

    flow_first<<<grd, blk, 0, stream>>>(flow, wsA, s);
    flow_mid<0><<<grd, blk, 0, stream>>>(wsA, out);
    flow_mid<0><<<grd, blk, 0, stream>>>(out, wsA);
    flow_mid<0><<<grd, blk, 0, stream>>>(wsA, out);
    flow_mid<0><<<grd, blk, 0, stream>>>(out, wsA);
    flow_mid<0><<<grd, blk, 0, stream>>>(wsA, out);
    flow_mid<0><<<grd, blk, 0, stream>>>(out, wsA);
    flow_mid<1><<<grd, blk, 0, stream>>>(wsA, out);
}

// Round 9
// 512.923 us; speedup vs baseline: 1.6854x; 1.0708x over previous
//
#include <hip/hip_runtime.h>

// FlowExp: v = flow/2^8; repeat 8x: v <- trilinear_pull(v, identity + v)
// Invariant: ||v||inf <= max|flow|/256 ~ 0.023 < 1 for all steps, so
// floor(x+vx) in {x-1, x}: sign tests instead of floor/mod/clamp, halo 1
// always covers the corners, out-of-bounds folded into z-weights (m=0).
//
// R9: flow_first was the last VGPR-round-trip staging kernel (160us vs 55us
// DMA mids). global_load_lds requires linear LDS dest (base + lane*4) but the
// GLOBAL source is per-lane -> gather planar flow straight into the SoA tile.
// The 1/256 scale is folded at consumption (displacement and final output).

#define BB 2
#define DD 160
#define HH 192
#define WW 160

constexpr int HW    = HH * WW;          // 30720
constexpr int PLANE = DD * HW;          // 4,915,200
constexpr int TX = 32, TY = 8, TZ = 8;
constexpr int SX = TX + 2, SY = TY + 2, SZ = TZ + 2;   // 34 x 10 x 10
constexpr int SYX = SY * SX;            // 340
constexpr int NW  = SZ * SYX;           // 3400 voxels per tile
constexpr int NF  = 3 * NW;             // 10200 floats per tile
constexpr int NFULL = NF / 256;         // 39 full 256-float DMA iterations
constexpr int NREM  = NF - NFULL * 256; // 216 remainder floats

__device__ __forceinline__ void gld_lds4(const float* g, float* l) {
    __builtin_amdgcn_global_load_lds(
        (const __attribute__((address_space(1))) void*)g,
        (__attribute__((address_space(3))) void*)l, 4, 0, 0);
}

// in-batch voxel offset for staging element `vox` of the tile (+border clamp)
__device__ __forceinline__ int stage_pa(int vox, int x0, int y0, int z0,
                                        int gb0, bool border) {
    const int szi = vox / SYX;
    const int r   = vox - szi * SYX;
    const int syi = r / SX;
    const int sxi = r - syi * SX;
    if (!border) return gb0 + szi * HW + syi * WW + sxi;
    const int gz = min(max(z0 - 1 + szi, 0), DD - 1);
    const int gy = min(max(y0 - 1 + syi, 0), HH - 1);
    const int gx = min(max(x0 - 1 + sxi, 0), WW - 1);
    return (gz * HH + gy) * WW + gx;
}

// ---------------- step 1: planar flow -> packed interleaved ----------------
// LDS holds RAW flow values (DMA can't scale); scale folded at consumption.
__global__ __launch_bounds__(256, 4) void flow_first(const float* __restrict__ vin,
                                                     float* __restrict__ vout,
                                                     float scale) {
    __shared__ float lds[NF];   // SoA: 3 planes of NW raw flow values
    const int tid = threadIdx.x;
    const int x0 = blockIdx.x * TX;
    const int y0 = blockIdx.y * TY;
    const int b  = blockIdx.z / (DD / TZ);
    const int z0 = (blockIdx.z % (DD / TZ)) * TZ;
    const bool border = (x0 == 0) | (x0 + TX >= WW) |
                        (y0 == 0) | (y0 + TY >= HH) |
                        (z0 == 0) | (z0 + TZ >= DD);
    const int gb0 = ((z0 - 1) * HH + (y0 - 1)) * WW + (x0 - 1);
    const float* vb = vin + (size_t)b * 3 * PLANE;

    // async DMA staging: LDS linear in tid; per-lane planar global address
    #pragma unroll 8
    for (int k = 0; k < NFULL; ++k) {
        const int i = tid + k * 256;
        const int ch  = i / NW;
        const int vox = i - ch * NW;
        const int pa  = stage_pa(vox, x0, y0, z0, gb0, border);
        gld_lds4(vb + (size_t)ch * PLANE + pa, &lds[i]);
    }
    if (tid < NREM) {   // tail via plain write
        const int i = tid + NFULL * 256;
        const int ch  = i / NW;
        const int vox = i - ch * NW;
        const int pa  = stage_pa(vox, x0, y0, z0, gb0, border);
        lds[i] = vb[(size_t)ch * PLANE + pa];
    }
    __syncthreads();

    const int tx = tid & (TX - 1), ty = tid >> 5;
    const int x = x0 + tx, y = y0 + ty;
    #pragma unroll 2
    for (int zz = 0; zz < TZ; ++zz) {
        const int z = z0 + zz;
        const int so = ((zz + 1) * SY + (ty + 1)) * SX + (tx + 1);
        const float vz = lds[so] * scale;           // scaled displacement
        const float vy = lds[NW + so] * scale;
        const float vx = lds[2 * NW + so] * scale;
        const float cz = (float)z + vz, cy = (float)y + vy, cx = (float)x + vx;
        const bool jz = vz < 0.f, jy = vy < 0.f, jx = vx < 0.f;
        const float gzf = jz ? vz + 1.f : vz;
        const float gyf = jy ? vy + 1.f : vy;
        const float gxf = jx ? vx + 1.f : vx;
        const bool inb = (cz >= 0.f) & (cz <= (float)(DD - 1)) &
                         (cy >= 0.f) & (cy <= (float)(HH - 1)) &
                         (cx >= 0.f) & (cx <= (float)(WW - 1));
        const float m = inb ? 1.f : 0.f;
        const float wz1 = gzf * m, wz0 = m - wz1;
        const float wy1 = gyf, wy0 = 1.f - gyf;
        const float wx1 = gxf, wx0 = 1.f - gxf;
        const int sb = ((so - (jx ? 1 : 0)) - (jy ? SX : 0)) - (jz ? SYX : 0);
        float oz = 0.f, oy = 0.f, ox = 0.f;
        #pragma unroll
        for (int dz = 0; dz < 2; ++dz) {
            const float wzv = dz ? wz1 : wz0;
            #pragma unroll
            for (int dy = 0; dy < 2; ++dy) {
                const float wzy = wzv * (dy ? wy1 : wy0);
                const float w0 = wzy * wx0, w1 = wzy * wx1;
                const int o = sb + dz * SYX + dy * SX;
                oz += lds[o] * w0;     oy += lds[NW + o] * w0;     ox += lds[2 * NW + o] * w0;
                oz += lds[o + 1] * w1; oy += lds[NW + o + 1] * w1; ox += lds[2 * NW + o + 1] * w1;
            }
        }
        // raw-value accumulation -> apply scale once (FP reorder << threshold)
        float t[3] = { oz * scale, oy * scale, ox * scale };
        __builtin_memcpy(vout + ((size_t)((b * DD + z) * HH + y) * WW + x) * 3, t, 12);
    }
}

// ------------- steps 2..8: packed interleaved in, DMA staging --------------
// OUT_PLANAR: final step writes (B,3,D,H,W)
template<int OUT_PLANAR>
__global__ __launch_bounds__(256, 4) void flow_mid(const float* __restrict__ vin,
                                                   float* __restrict__ vout) {
    __shared__ float lds[NF];   // interleaved: voxel v -> floats 3v..3v+2
    const int tid = threadIdx.x;
    const int x0 = blockIdx.x * TX;
    const int y0 = blockIdx.y * TY;
    const int b  = blockIdx.z / (DD / TZ);
    const int z0 = (blockIdx.z % (DD / TZ)) * TZ;
    const bool border = (x0 == 0) | (x0 + TX >= WW) |
                        (y0 == 0) | (y0 + TY >= HH) |
                        (z0 == 0) | (z0 + TZ >= DD);
    const int gb0 = ((z0 - 1) * HH + (y0 - 1)) * WW + (x0 - 1);
    const float* vb = vin + (size_t)b * PLANE * 3;

    // async DMA staging: LDS linear == global interleaved order
    #pragma unroll 8
    for (int k = 0; k < NFULL; ++k) {
        const int i = tid + k * 256;
        const int vox = i / 3;
        const int ch  = i - vox * 3;
        const int pa  = stage_pa(vox, x0, y0, z0, gb0, border);
        gld_lds4(vb + (size_t)pa * 3 + ch, &lds[i]);
    }
    if (tid < NREM) {   // tail via plain write (DMA dest is HW-linear)
        const int i = tid + NFULL * 256;
        const int vox = i / 3;
        const int ch  = i - vox * 3;
        const int pa  = stage_pa(vox, x0, y0, z0, gb0, border);
        lds[i] = vb[(size_t)pa * 3 + ch];
    }
    __syncthreads();

    const int tx = tid & (TX - 1), ty = tid >> 5;
    const int x = x0 + tx, y = y0 + ty;
    #pragma unroll 2
    for (int zz = 0; zz < TZ; ++zz) {
        const int z = z0 + zz;
        const int so = ((zz + 1) * SY + (ty + 1)) * SX + (tx + 1);
        const float vz = lds[3 * so], vy = lds[3 * so + 1], vx = lds[3 * so + 2];
        const float cz = (float)z + vz, cy = (float)y + vy, cx = (float)x + vx;
        const bool jz = vz < 0.f, jy = vy < 0.f, jx = vx < 0.f;
        const float gzf = jz ? vz + 1.f : vz;
        const float gyf = jy ? vy + 1.f : vy;
        const float gxf = jx ? vx + 1.f : vx;
        const bool inb = (cz >= 0.f) & (cz <= (float)(DD - 1)) &
                         (cy >= 0.f) & (cy <= (float)(HH - 1)) &
                         (cx >= 0.f) & (cx <= (float)(WW - 1));
        const float m = inb ? 1.f : 0.f;
        const float wz1 = gzf * m, wz0 = m - wz1;
        const float wy1 = gyf, wy0 = 1.f - gyf;
        const float wx1 = gxf, wx0 = 1.f - gxf;
        const int sb = ((so - (jx ? 1 : 0)) - (jy ? SX : 0)) - (jz ? SYX : 0);
        float oz = 0.f, oy = 0.f, ox = 0.f;
        #pragma unroll
        for (int dz = 0; dz < 2; ++dz) {
            const float wzv = dz ? wz1 : wz0;
            #pragma unroll
            for (int dy = 0; dy < 2; ++dy) {
                const float wzy = wzv * (dy ? wy1 : wy0);
                const float w0 = wzy * wx0, w1 = wzy * wx1;
                const int ob = 3 * (sb + dz * SYX + dy * SX);
                oz += lds[ob]     * w0; oy += lds[ob + 1] * w0; ox += lds[ob + 2] * w0;
                oz += lds[ob + 3] * w1; oy += lds[ob + 4] * w1; ox += lds[ob + 5] * w1;
            }
        }
        if (OUT_PLANAR) {
            float* op = vout + (size_t)b * 3 * PLANE + (z * HH + y) * WW + x;
            op[0] = oz; op[PLANE] = oy; op[2 * PLANE] = ox;
        } else {
            float t[3] = { oz, oy, ox };
            __builtin_memcpy(vout + ((size_t)((b * DD + z) * HH + y) * WW + x) * 3, t, 12);
        }
    }
}

extern "C" void kernel_launch(void* const* d_in, const int* in_sizes, int n_in,
                              void* d_out, int out_size, void* d_ws, size_t ws_size,
                              hipStream_t stream) {
    const float* flow = (const float*)d_in[0];
    float* out = (float*)d_out;   // packed scratch for even steps + final planar
    float* wsA = (float*)d_ws;    // packed scratch (118 MB)

    dim3 blk(256);
    dim3 grd(WW / TX, HH / TY, (DD / TZ) * BB);   // 5 x 24 x 40
    const float s = 1.f / 256.f;                  // 1 / 2^NSTEPS

    flow_first<<<grd, blk, 0, stream>>>(flow, wsA, s);
    flow_mid<0><<<grd, blk, 0, stream>>>(wsA, out);
    flow_mid<0><<<grd, blk, 0, stream>>>(out, wsA);
    flow_mid<0><<<grd, blk, 0, stream>>>(wsA, out);
    flow_mid<0><<<grd, blk, 0, stream>>>(out, wsA);
    flow_mid<0><<<grd, blk, 0, stream>>>(wsA, out);
    flow_mid<0><<<grd, blk, 0, stream>>>(out, wsA);
    flow_mid<1><<<grd, blk, 0, stream>>>(wsA, out);
}